// Round 16
// baseline (5375.940 us; speedup 1.0000x reference)
//
#include <hip/hip_runtime.h>
#include <hip/hip_bf16.h>

#define T_SEQ 2048
#define HID 128
#define G4 512           // 4*HID gates
#define N_NODES 50000
#define N_EDGES 800000

typedef float f32x4 __attribute__((ext_vector_type(4)));
typedef _Float16 f16x2 __attribute__((ext_vector_type(2)));
typedef _Float16 f16x8 __attribute__((ext_vector_type(8)));

__device__ __forceinline__ float fast_sigmoid(float x) {
    return 1.0f / (1.0f + __expf(-x));
}
__device__ __forceinline__ float fast_tanh(float x) {
    return 1.0f - 2.0f / (__expf(2.0f * x) + 1.0f);
}

__device__ __forceinline__ float dot2_f16(float bits_w, f16x2 h2, float acc) {
    f16x2 w2 = __builtin_bit_cast(f16x2, bits_w);
#if __has_builtin(__builtin_amdgcn_fdot2)
    return __builtin_amdgcn_fdot2(w2, h2, acc, false);
#else
    asm("v_dot2_f32_f16 %0, %1, %2, %0" : "+v"(acc) : "v"(w2), "v"(h2));
    return acc;
#endif
}

// ---------------- xg precompute, layer 0 (Din=17) ----------------
__global__ void xg0_kernel(const float* __restrict__ g_mol,
                           const float* __restrict__ wf, const float* __restrict__ bfi, const float* __restrict__ bfh,
                           const float* __restrict__ wr, const float* __restrict__ bri, const float* __restrict__ brh,
                           float* __restrict__ xg_f, float* __restrict__ xg_r)
{
    int gid = blockIdx.x * blockDim.x + threadIdx.x;
    int j = gid & (G4 - 1);
    int rest = gid >> 9;
    int t = rest & (T_SEQ - 1);
    int dir = rest >> 11;
    const float* w  = dir ? wr  : wf;
    const float* bi = dir ? bri : bfi;
    const float* bh = dir ? brh : bfh;
    float* xg = dir ? xg_r : xg_f;
    const float* x  = g_mol + t * 17;
    const float* wj = w + j * 17;
    float acc = bi[j] + bh[j];
    #pragma unroll
    for (int k = 0; k < 17; ++k) acc += x[k] * wj[k];
    xg[t * G4 + j] = acc;
}

// ---------------- CSR build: histogram (by dst) + out-weight (by src) ----------------
#define EDGE_BLOCKS ((N_EDGES + 1023) / 1024)
__global__ void hist_kernel(const int* __restrict__ esrc, const int* __restrict__ edst,
                            const float* __restrict__ ew,
                            int* __restrict__ cnt, float* __restrict__ outw)
{
    int e = blockIdx.x * 1024 + threadIdx.x;
    if (e < N_EDGES) {
        atomicAdd(&cnt[edst[e]], 1);
        atomicAdd(&outw[esrc[e]], ew[e]);
    }
}

// single-block exclusive prefix over cnt -> offs, cursor
__global__ __launch_bounds__(1024)
void prefix_kernel(const int* __restrict__ cnt, int* __restrict__ offs, int* __restrict__ cursor)
{
    __shared__ int part[1024];
    const int tid = threadIdx.x;
    const int CH = (N_NODES + 1023) / 1024;   // 49
    int base = tid * CH;
    int sum = 0;
    for (int i = 0; i < CH; ++i) { int idx = base + i; if (idx < N_NODES) sum += cnt[idx]; }
    part[tid] = sum;
    __syncthreads();
    for (int d = 1; d < 1024; d <<= 1) {
        int v = (tid >= d) ? part[tid - d] : 0;
        __syncthreads();
        part[tid] += v;
        __syncthreads();
    }
    int run = (tid == 0) ? 0 : part[tid - 1];
    for (int i = 0; i < CH; ++i) {
        int idx = base + i;
        if (idx < N_NODES) { offs[idx] = run; cursor[idx] = run; run += cnt[idx]; }
    }
    if (tid == 1023) offs[N_NODES] = run;
}

__global__ void reorder_kernel(const int* __restrict__ esrc, const int* __restrict__ edst,
                               const float* __restrict__ ew, int* __restrict__ cursor,
                               int* __restrict__ csr_src, float* __restrict__ csr_w)
{
    int e = blockIdx.x * 1024 + threadIdx.x;
    if (e < N_EDGES) {
        int pos = atomicAdd(&cursor[edst[e]], 1);
        csr_src[pos] = esrc[e];
        csr_w[pos]   = ew[e];
    }
}

// ---------------- LSTM scan v4: 1 barrier/step, wave-local gates ----------------
// 512 working threads (8 waves); threads 512-1023 are barrier companions.
// Thread: u = (wave<<4)|(lane&15), g = lane>>4, row j = g*128+u — full 128-k
// dot per thread, 64 f16-pair weights in AGPRs. The 4 gates of unit u live in
// lanes l, l^16, l^32, l^48 of the SAME wave: combine = 3 parallel shfl_xor
// (no LDS partials, no extra barrier). All lanes compute the activation
// redundantly (gate_k = arr[g^k]); g==0 lanes write h. ONE barrier per step.
struct ScanSmem {
    _Float16 h16[2][HID] __attribute__((aligned(16)));
};

#define P64(M) M(0) M(1) M(2) M(3) M(4) M(5) M(6) M(7) M(8) M(9) M(10) M(11) \
               M(12) M(13) M(14) M(15) M(16) M(17) M(18) M(19) M(20) M(21) M(22) M(23) \
               M(24) M(25) M(26) M(27) M(28) M(29) M(30) M(31) M(32) M(33) M(34) M(35) \
               M(36) M(37) M(38) M(39) M(40) M(41) M(42) M(43) M(44) M(45) M(46) M(47) \
               M(48) M(49) M(50) M(51) M(52) M(53) M(54) M(55) M(56) M(57) M(58) M(59) \
               M(60) M(61) M(62) M(63)
#define B16(M) M(0,0,1,2,3) M(1,4,5,6,7) M(2,8,9,10,11) M(3,12,13,14,15) \
               M(4,16,17,18,19) M(5,20,21,22,23) M(6,24,25,26,27) M(7,28,29,30,31) \
               M(8,32,33,34,35) M(9,36,37,38,39) M(10,40,41,42,43) M(11,44,45,46,47) \
               M(12,48,49,50,51) M(13,52,53,54,55) M(14,56,57,58,59) M(15,60,61,62,63)

__device__ __forceinline__ void lstm_scan_dev(ScanSmem* sm, int dir,
                                              const float* __restrict__ xg,
                                              const float* __restrict__ whh,
                                              float* __restrict__ out,
                                              float* __restrict__ gvec, int write_out)
{
    const int tid = threadIdx.x;
    if (tid >= 512) {                          // barrier companion waves
        for (int s = 0; s <= T_SEQ; ++s) __syncthreads();
        return;
    }
    const int l = tid & 63;
    const int w = tid >> 6;                    // wave 0..7
    const int u = (w << 4) | (l & 15);         // hidden unit 0..127
    const int g = l >> 4;                      // gate 0..3
    const int j = g * HID + u;                 // gate row 0..511

    const float* wptr = whh + j * HID;

    // 64 f16-pair weights (full row) pinned in AGPRs.
#define DECL_PK(p) float apk##p; { \
    f16x2 pk_ = { (_Float16)wptr[2*(p)], (_Float16)wptr[2*(p)+1] }; \
    float bits_ = __builtin_bit_cast(float, pk_); \
    asm volatile("v_accvgpr_write_b32 %0, %1" : "=a"(apk##p) : "v"(bits_)); }
    P64(DECL_PK)
#undef DECL_PK

    if (tid < HID) sm->h16[0][tid] = (_Float16)0.0f;
    float c = 0.0f;
    float msum = 0.0f;
    __syncthreads();                           // barrier #0

    int t0 = dir ? (T_SEQ - 1) : 0;
    float xv = xg[t0 * G4 + j];                // prefetched input-gate term (all lanes)

    int pp = 0;
    for (int s = 0; s < T_SEQ; ++s) {
        int s2 = (s + 1 < T_SEQ) ? (s + 1) : s;
        int t      = dir ? (T_SEQ - 1 - s)  : s;
        int t_next = dir ? (T_SEQ - 1 - s2) : s2;
        float xv_n = xg[t_next * G4 + j];      // prefetch next step

        const f16x8* h16v = reinterpret_cast<const f16x8*>(&sm->h16[pp][0]);
        float acc0 = 0.f, acc1 = 0.f, acc2 = 0.f, acc3 = 0.f;
#define DOT_BLK(i, q0, q1, q2, q3) { f16x8 hv = h16v[i]; float b0_, b1_, b2_, b3_; \
        asm volatile("v_accvgpr_read_b32 %0, %1" : "=v"(b0_) : "a"(apk##q0)); \
        asm volatile("v_accvgpr_read_b32 %0, %1" : "=v"(b1_) : "a"(apk##q1)); \
        asm volatile("v_accvgpr_read_b32 %0, %1" : "=v"(b2_) : "a"(apk##q2)); \
        asm volatile("v_accvgpr_read_b32 %0, %1" : "=v"(b3_) : "a"(apk##q3)); \
        f16x2 h0_ = { hv[0], hv[1] }, h1_ = { hv[2], hv[3] }; \
        f16x2 h2_ = { hv[4], hv[5] }, h3_ = { hv[6], hv[7] }; \
        acc0 = dot2_f16(b0_, h0_, acc0); acc1 = dot2_f16(b1_, h1_, acc1); \
        acc2 = dot2_f16(b2_, h2_, acc2); acc3 = dot2_f16(b3_, h3_, acc3); }
        B16(DOT_BLK)
#undef DOT_BLK
        float p = (acc0 + acc1) + (acc2 + acc3) + xv;

        // gate combine: 3 parallel xor-shuffles within the wave
        float v1 = __shfl_xor(p, 16, 64);      // gate g^1, same unit
        float v2 = __shfl_xor(p, 32, 64);      // gate g^2
        float v3 = __shfl_xor(p, 48, 64);      // gate g^3
        // arr[idx] holds gate (g ^ idx); gate_k = arr[g ^ k]
        float gi, gf, gg_, go;
        {
            int s0 = g;            gi  = s0 == 0 ? p : s0 == 1 ? v1 : s0 == 2 ? v2 : v3;
            int s1 = g ^ 1;        gf  = s1 == 0 ? p : s1 == 1 ? v1 : s1 == 2 ? v2 : v3;
            int s2_ = g ^ 2;       gg_ = s2_ == 0 ? p : s2_ == 1 ? v1 : s2_ == 2 ? v2 : v3;
            int s3 = g ^ 3;        go  = s3 == 0 ? p : s3 == 1 ? v1 : s3 == 2 ? v2 : v3;
        }
        float ig = fast_sigmoid(gi);
        float fg = fast_sigmoid(gf);
        float gt = fast_tanh(gg_);
        float og = fast_sigmoid(go);
        c = fg * c + ig * gt;                  // replicated x4 per unit (identical)
        float hh = og * fast_tanh(c);
        if (g == 0) {
            sm->h16[pp ^ 1][u] = (_Float16)hh;
            if (write_out) out[t * HID + u] = hh;
            msum += hh;
        }
        __syncthreads();                       // the ONLY barrier per step
        pp ^= 1;
        xv = xv_n;
    }
    if (gvec != nullptr && g == 0) gvec[dir * HID + u] = msum * (1.0f / (float)T_SEQ);
}

// ---------------- Combined1: blocks 0-1 = LSTM layer0 scan, rest = CSR gather ----------------
// Volatile 80KB pad keeps 1 block/CU (scan CU-exclusivity: R14-confirmed).
#define GATHER_BLOCKS (N_NODES / 16)          // 3125, 16 waves/block = 1 node/wave
__global__ __launch_bounds__(1024, 1)
void combined1(const float* __restrict__ xg_f, const float* __restrict__ xg_r,
               const float* __restrict__ whh_f, const float* __restrict__ whh_r,
               float* __restrict__ out_f, float* __restrict__ out_r,
               const int* __restrict__ offs, const int* __restrict__ csr_src,
               const float* __restrict__ csr_w, const float* __restrict__ feat,
               float* __restrict__ agg)
{
    __shared__ ScanSmem ssm;
    __shared__ float pad_iso[20480];          // 80 KB occupancy limiter
    volatile float* vpad = pad_iso;           // volatile store: never DCE'd
    vpad[threadIdx.x] = 0.0f;
    int bid = blockIdx.x;
    int tid = threadIdx.x;
    if (bid < 2) {
        lstm_scan_dev(&ssm, bid, bid ? xg_r : xg_f, bid ? whh_r : whh_f,
                      bid ? out_r : out_f, nullptr, 1);
        return;
    }
    // gather path: wave (tid>>6) of this block owns one node
    int n = (bid - 2) * 16 + (tid >> 6);
    int lane = tid & 63;
    int start = offs[n], end = offs[n + 1];
    float ax = 0.0f, ay = 0.0f;
    const float2* f2 = reinterpret_cast<const float2*>(feat);
    for (int e = start; e < end; ++e) {
        int src = csr_src[e];                 // wave-uniform (broadcast)
        float wgt = csr_w[e];
        float2 v = f2[(long)src * 64 + lane]; // coalesced 512B row across wave
        ax += wgt * v.x; ay += wgt * v.y;
    }
    float2 o; o.x = ax; o.y = ay;
    reinterpret_cast<float2*>(agg)[(long)n * 64 + lane] = o;
}

// ---------------- Combined2: blocks <512 = xg1, rest = gconv1 (W1 in LDS) ----------------
#define XG1_BLOCKS 512                        // 2*512*512 threads / 1024
#define NPB2 96
#define G1_BLOCKS ((N_NODES + NPB2 - 1) / NPB2)  // 521
__global__ __launch_bounds__(1024, 1)
void combined2(const float* __restrict__ hf0, const float* __restrict__ hr0,
               const float* __restrict__ wf, const float* __restrict__ bfi, const float* __restrict__ bfh,
               const float* __restrict__ wr, const float* __restrict__ bri, const float* __restrict__ brh,
               float* __restrict__ xg_f, float* __restrict__ xg_r,
               const float* __restrict__ W1, const float* __restrict__ b1,
               float* __restrict__ agg)
{
    __shared__ float w_s[128 * 128];          // 64 KB (gconv1 path)
    __shared__ float row_s[8][HID];
    int bid = blockIdx.x;
    int tid = threadIdx.x;
    if (bid < XG1_BLOCKS) {
        // ---- xg1 path ----
        int gid = bid * 1024 + tid;
        int j = gid & (G4 - 1);
        int rest = gid >> 9;
        int tb = rest & 511;
        int dir = rest >> 9;
        const float* w  = dir ? wr  : wf;
        const float* bi = dir ? bri : bfi;
        const float* bh = dir ? brh : bfh;
        float* xg = dir ? xg_r : xg_f;
        int t0 = tb * 4;

        float b = bi[j] + bh[j];
        float a0 = b, a1 = b, a2 = b, a3 = b;
        const float4* wrow = reinterpret_cast<const float4*>(w + j * 256);
        const float4* hf = reinterpret_cast<const float4*>(hf0 + t0 * HID);
        const float4* hr = reinterpret_cast<const float4*>(hr0 + t0 * HID);
        #pragma unroll 8
        for (int k = 0; k < 32; ++k) {
            float4 wv = wrow[k];
            float4 v0 = hf[k], v1 = hf[32 + k], v2 = hf[64 + k], v3 = hf[96 + k];
            a0 += wv.x*v0.x + wv.y*v0.y + wv.z*v0.z + wv.w*v0.w;
            a1 += wv.x*v1.x + wv.y*v1.y + wv.z*v1.z + wv.w*v1.w;
            a2 += wv.x*v2.x + wv.y*v2.y + wv.z*v2.z + wv.w*v2.w;
            a3 += wv.x*v3.x + wv.y*v3.y + wv.z*v3.z + wv.w*v3.w;
        }
        #pragma unroll 8
        for (int k = 0; k < 32; ++k) {
            float4 wv = wrow[32 + k];
            float4 v0 = hr[k], v1 = hr[32 + k], v2 = hr[64 + k], v3 = hr[96 + k];
            a0 += wv.x*v0.x + wv.y*v0.y + wv.z*v0.z + wv.w*v0.w;
            a1 += wv.x*v1.x + wv.y*v1.y + wv.z*v1.z + wv.w*v1.w;
            a2 += wv.x*v2.x + wv.y*v2.y + wv.z*v2.z + wv.w*v2.w;
            a3 += wv.x*v3.x + wv.y*v3.y + wv.z*v3.z + wv.w*v3.w;
        }
        xg[(t0 + 0) * G4 + j] = a0;
        xg[(t0 + 1) * G4 + j] = a1;
        xg[(t0 + 2) * G4 + j] = a2;
        xg[(t0 + 3) * G4 + j] = a3;
        return;
    }
    // ---- gconv1 path: linear+relu in-place on agg ----
    int gb = bid - XG1_BLOCKS;
    int j = tid & 127;
    int sub = tid >> 7;                        // 0..7 rows in flight
    for (int i = tid; i < 128 * 128; i += 1024) w_s[i] = W1[i];
    float bj = b1[j];
    __syncthreads();
    int base = gb * NPB2;
    for (int n0 = base; n0 < base + NPB2; n0 += 8) {
        int row = n0 + sub;
        bool valid = row < N_NODES;
        if (valid) row_s[sub][j] = agg[(long)row * HID + j];
        __syncthreads();
        float a = bj;
        #pragma unroll 8
        for (int k = 0; k < 128; ++k) a += row_s[sub][k] * w_s[k * 128 + j];
        __syncthreads();
        if (valid) agg[(long)row * HID + j] = fmaxf(a, 0.0f);
    }
}

// ---------------- Combined3: blocks 0-1 = LSTM layer1 scan, rest = outw reduce ----------------
#define RED_BLOCKS 512
__global__ __launch_bounds__(1024, 4)
void combined3(const float* __restrict__ xg_f, const float* __restrict__ xg_r,
               const float* __restrict__ whh_f, const float* __restrict__ whh_r,
               float* __restrict__ gvec,
               const float* __restrict__ outw, const float* __restrict__ h,
               float* __restrict__ s_out)
{
    __shared__ ScanSmem ssm;
    __shared__ float red[8 * 128];
    int bid = blockIdx.x;
    int tid = threadIdx.x;
    if (bid < 2) {
        lstm_scan_dev(&ssm, bid, bid ? xg_r : xg_f, bid ? whh_r : whh_f,
                      nullptr, gvec, 0);
        return;
    }
    int hb = bid - 2;                          // 0..RED_BLOCKS-1
    int f = tid & 127;
    int r = tid >> 7;                          // 0..7
    float acc = 0.0f;
    for (int n = hb * 8 + r; n < N_NODES; n += RED_BLOCKS * 8)
        acc += outw[n] * h[(long)n * HID + f];
    red[r * 128 + f] = acc;
    __syncthreads();
    if (tid < 128) {
        float s = 0.0f;
        #pragma unroll
        for (int rr = 0; rr < 8; ++rr) s += red[rr * 128 + tid];
        atomicAdd(&s_out[tid], s);
    }
}

// ---------------- head: hg = (s/N)@W2 + b2; concat; 4-layer MLP ----------------
__global__ __launch_bounds__(640)
void head_kernel(const float* __restrict__ s_in, const float* __restrict__ W2, const float* __restrict__ b2,
                 const float* __restrict__ gvec, const float* __restrict__ kmer,
                 const float* __restrict__ fc1w, const float* __restrict__ fc1b,
                 const float* __restrict__ fc2w, const float* __restrict__ fc2b,
                 const float* __restrict__ fc3w, const float* __restrict__ fc3b,
                 const float* __restrict__ fc4w, const float* __restrict__ fc4b,
                 float* __restrict__ out)
{
    __shared__ float feat[1152];
    __shared__ float a1[576];
    __shared__ float a2[256];
    __shared__ float a3[64];
    int tid = threadIdx.x;
    if (tid < 256) {
        float acc = b2[tid];
        const float inv_n = 1.0f / (float)N_NODES;
        for (int k = 0; k < HID; ++k)
            acc += (s_in[k] * inv_n) * W2[k * 256 + tid];
        feat[tid] = acc;
    } else if (tid < 512) {
        feat[tid] = gvec[tid - 256];
    }
    if (tid < 638) feat[512 + tid] = kmer[tid];
    __syncthreads();

    if (tid < 575) {
        const float2* wr = reinterpret_cast<const float2*>(fc1w + (long)tid * 1150);
        const float2* f2 = reinterpret_cast<const float2*>(feat);
        float acc = fc1b[tid];
        for (int k = 0; k < 575; ++k) {
            float2 wv = wr[k]; float2 fv = f2[k];
            acc += wv.x * fv.x + wv.y * fv.y;
        }
        a1[tid] = fmaxf(acc, 0.0f);
    }
    __syncthreads();
    if (tid < 256) {
        const float* wr = fc2w + (long)tid * 575;
        float acc = fc2b[tid];
        for (int k = 0; k < 575; ++k) acc += a1[k] * wr[k];
        a2[tid] = fmaxf(acc, 0.0f);
    }
    __syncthreads();
    if (tid < 64) {
        const float4* wr = reinterpret_cast<const float4*>(fc3w + (long)tid * 256);
        const float4* av4 = reinterpret_cast<const float4*>(a2);
        float acc = fc3b[tid];
        for (int k = 0; k < 64; ++k) {
            float4 wv = wr[k]; float4 av = av4[k];
            acc += wv.x*av.x + wv.y*av.y + wv.z*av.z + wv.w*av.w;
        }
        a3[tid] = fmaxf(acc, 0.0f);
    }
    __syncthreads();
    if (tid == 0) {
        float acc = fc4b[0];
        for (int k = 0; k < 64; ++k) acc += a3[k] * fc4w[k];
        out[0] = acc;
    }
}

extern "C" void kernel_launch(void* const* d_in, const int* in_sizes, int n_in,
                              void* d_out, int out_size, void* d_ws, size_t ws_size,
                              hipStream_t stream)
{
    const float* g_mol = (const float*)d_in[0];
    const float* feat  = (const float*)d_in[1];
    const int*   esrc  = (const int*)d_in[2];
    const int*   edst  = (const int*)d_in[3];
    const float* ew    = (const float*)d_in[4];
    const float* kmer  = (const float*)d_in[5];
    const float* w_ih_l0  = (const float*)d_in[6];
    const float* w_hh_l0  = (const float*)d_in[7];
    const float* b_ih_l0  = (const float*)d_in[8];
    const float* b_hh_l0  = (const float*)d_in[9];
    const float* w_ih_l0r = (const float*)d_in[10];
    const float* w_hh_l0r = (const float*)d_in[11];
    const float* b_ih_l0r = (const float*)d_in[12];
    const float* b_hh_l0r = (const float*)d_in[13];
    const float* w_ih_l1  = (const float*)d_in[14];
    const float* w_hh_l1  = (const float*)d_in[15];
    const float* b_ih_l1  = (const float*)d_in[16];
    const float* b_hh_l1  = (const float*)d_in[17];
    const float* w_ih_l1r = (const float*)d_in[18];
    const float* w_hh_l1r = (const float*)d_in[19];
    const float* b_ih_l1r = (const float*)d_in[20];
    const float* b_hh_l1r = (const float*)d_in[21];
    const float* W1 = (const float*)d_in[22];
    const float* b1 = (const float*)d_in[23];
    const float* W2 = (const float*)d_in[24];
    const float* b2 = (const float*)d_in[25];
    const float* fc1w = (const float*)d_in[26];
    const float* fc1b = (const float*)d_in[27];
    const float* fc2w = (const float*)d_in[28];
    const float* fc2b = (const float*)d_in[29];
    const float* fc3w = (const float*)d_in[30];
    const float* fc3b = (const float*)d_in[31];
    const float* fc4w = (const float*)d_in[32];
    const float* fc4b = (const float*)d_in[33];

    float* ws  = (float*)d_ws;
    float* XGF  = ws;                          // [2048*512]
    float* XGR  = XGF + T_SEQ * G4;            // [2048*512]
    float* HF0  = XGR + T_SEQ * G4;            // [2048*128]
    float* HR0  = HF0 + T_SEQ * HID;           // [2048*128]
    float* GVEC = HR0 + T_SEQ * HID;           // [256]
    float* SUM  = GVEC + 256;                  // [128]
    float* AGG  = SUM + 128;                   // [50000*128]
    float* OUTW = AGG + (size_t)N_NODES * HID; // [50000]
    float* CSRW = OUTW + N_NODES;              // [800000]
    int*   CNT  = (int*)(CSRW + N_EDGES);      // [50001]
    int*   OFFS = CNT + (N_NODES + 4);         // [50001]
    int*   CURS = OFFS + (N_NODES + 4);        // [50001]
    int*   CSRS = CURS + (N_NODES + 4);        // [800000]

    hipMemsetAsync(SUM, 0, 128 * sizeof(float), stream);
    hipMemsetAsync(OUTW, 0, N_NODES * sizeof(float), stream);
    hipMemsetAsync(CNT, 0, (N_NODES + 4) * sizeof(int), stream);

    // 0. CSR build (by dst) + out-weight (by src)
    hist_kernel<<<EDGE_BLOCKS, 1024, 0, stream>>>(esrc, edst, ew, CNT, OUTW);
    prefix_kernel<<<1, 1024, 0, stream>>>(CNT, OFFS, CURS);
    reorder_kernel<<<EDGE_BLOCKS, 1024, 0, stream>>>(esrc, edst, ew, CURS, CSRS, CSRW);

    // 1. xg0 (layer-0 input gates)
    xg0_kernel<<<(2 * T_SEQ * G4) / 256, 256, 0, stream>>>(
        g_mol, w_ih_l0, b_ih_l0, b_hh_l0, w_ih_l0r, b_ih_l0r, b_hh_l0r, XGF, XGR);

    // 2. scan layer0 (2 blocks, CU-exclusive) || CSR gather hop1 (no atomics)
    combined1<<<2 + GATHER_BLOCKS, 1024, 0, stream>>>(
        XGF, XGR, w_hh_l0, w_hh_l0r, HF0, HR0, OFFS, CSRS, CSRW, feat, AGG);

    // 3. xg1 (512 blocks, needs scan0) || gconv1 (521 blocks, needs gather)
    combined2<<<XG1_BLOCKS + G1_BLOCKS, 1024, 0, stream>>>(
        HF0, HR0, w_ih_l1, b_ih_l1, b_hh_l1, w_ih_l1r, b_ih_l1r, b_hh_l1r,
        XGF, XGR, W1, b1, AGG);

    // 4. scan layer1 (2 blocks) || outw-weighted node reduce (needs gconv1)
    combined3<<<2 + RED_BLOCKS, 1024, 0, stream>>>(
        XGF, XGR, w_hh_l1, w_hh_l1r, GVEC, OUTW, AGG, SUM);

    // 5. head
    head_kernel<<<1, 640, 0, stream>>>(SUM, W2, b2, GVEC, kmer,
                                       fc1w, fc1b, fc2w, fc2b, fc3w, fc3b, fc4w, fc4b,
                                       (float*)d_out);
}

// Round 17
// 4572.987 us; speedup vs baseline: 1.1756x; 1.1756x over previous
//
#include <hip/hip_runtime.h>
#include <hip/hip_bf16.h>

#define T_SEQ 2048
#define HID 128
#define G4 512           // 4*HID gates
#define N_NODES 50000
#define N_EDGES 800000

typedef float f32x4 __attribute__((ext_vector_type(4)));
typedef _Float16 f16x2 __attribute__((ext_vector_type(2)));
typedef _Float16 f16x8 __attribute__((ext_vector_type(8)));

__device__ __forceinline__ float fast_sigmoid(float x) {
    return 1.0f / (1.0f + __expf(-x));
}
__device__ __forceinline__ float fast_tanh(float x) {
    return 1.0f - 2.0f / (__expf(2.0f * x) + 1.0f);
}

__device__ __forceinline__ float dot2_f16(float bits_w, f16x2 h2, float acc) {
    f16x2 w2 = __builtin_bit_cast(f16x2, bits_w);
#if __has_builtin(__builtin_amdgcn_fdot2)
    return __builtin_amdgcn_fdot2(w2, h2, acc, false);
#else
    asm("v_dot2_f32_f16 %0, %1, %2, %0" : "+v"(acc) : "v"(w2), "v"(h2));
    return acc;
#endif
}

// ---------------- xg precompute, layer 0 (Din=17) ----------------
__global__ void xg0_kernel(const float* __restrict__ g_mol,
                           const float* __restrict__ wf, const float* __restrict__ bfi, const float* __restrict__ bfh,
                           const float* __restrict__ wr, const float* __restrict__ bri, const float* __restrict__ brh,
                           float* __restrict__ xg_f, float* __restrict__ xg_r)
{
    int gid = blockIdx.x * blockDim.x + threadIdx.x;
    int j = gid & (G4 - 1);
    int rest = gid >> 9;
    int t = rest & (T_SEQ - 1);
    int dir = rest >> 11;
    const float* w  = dir ? wr  : wf;
    const float* bi = dir ? bri : bfi;
    const float* bh = dir ? brh : bfh;
    float* xg = dir ? xg_r : xg_f;
    const float* x  = g_mol + t * 17;
    const float* wj = w + j * 17;
    float acc = bi[j] + bh[j];
    #pragma unroll
    for (int k = 0; k < 17; ++k) acc += x[k] * wj[k];
    xg[t * G4 + j] = acc;
}

// ---------------- CSR build: histogram (by dst) + out-weight (by src) ----------------
#define EDGE_BLOCKS ((N_EDGES + 1023) / 1024)
__global__ void hist_kernel(const int* __restrict__ esrc, const int* __restrict__ edst,
                            const float* __restrict__ ew,
                            int* __restrict__ cnt, float* __restrict__ outw)
{
    int e = blockIdx.x * 1024 + threadIdx.x;
    if (e < N_EDGES) {
        atomicAdd(&cnt[edst[e]], 1);
        atomicAdd(&outw[esrc[e]], ew[e]);
    }
}

// single-block exclusive prefix over cnt -> offs, cursor
__global__ __launch_bounds__(1024)
void prefix_kernel(const int* __restrict__ cnt, int* __restrict__ offs, int* __restrict__ cursor)
{
    __shared__ int part[1024];
    const int tid = threadIdx.x;
    const int CH = (N_NODES + 1023) / 1024;   // 49
    int base = tid * CH;
    int sum = 0;
    for (int i = 0; i < CH; ++i) { int idx = base + i; if (idx < N_NODES) sum += cnt[idx]; }
    part[tid] = sum;
    __syncthreads();
    for (int d = 1; d < 1024; d <<= 1) {
        int v = (tid >= d) ? part[tid - d] : 0;
        __syncthreads();
        part[tid] += v;
        __syncthreads();
    }
    int run = (tid == 0) ? 0 : part[tid - 1];
    for (int i = 0; i < CH; ++i) {
        int idx = base + i;
        if (idx < N_NODES) { offs[idx] = run; cursor[idx] = run; run += cnt[idx]; }
    }
    if (tid == 1023) offs[N_NODES] = run;
}

__global__ void reorder_kernel(const int* __restrict__ esrc, const int* __restrict__ edst,
                               const float* __restrict__ ew, int* __restrict__ cursor,
                               int* __restrict__ csr_src, float* __restrict__ csr_w)
{
    int e = blockIdx.x * 1024 + threadIdx.x;
    if (e < N_EDGES) {
        int pos = atomicAdd(&cursor[edst[e]], 1);
        csr_src[pos] = esrc[e];
        csr_w[pos]   = ew[e];
    }
}

// ---------------- shared-memory layout + device scan (R11/R15 dot2+AGPR engine) ----------------
// R16 lesson: do NOT replicate activation across lanes (quarter-rate trans pipe
// x8 waves = +640 cyc) and do NOT put shuffles in the serial path (R10).
// This 2-barrier, 16-wave, 2-wave-activation structure is the proven best.
struct ScanSmem {
    _Float16 h16[2][HID] __attribute__((aligned(16)));
    float g[G4];
    float part[G4];
};

#define B8(M) M(0,0,1,2,3) M(1,4,5,6,7) M(2,8,9,10,11) M(3,12,13,14,15) \
              M(4,16,17,18,19) M(5,20,21,22,23) M(6,24,25,26,27) M(7,28,29,30,31)
#define P32(M) M(0) M(1) M(2) M(3) M(4) M(5) M(6) M(7) M(8) M(9) M(10) M(11) \
               M(12) M(13) M(14) M(15) M(16) M(17) M(18) M(19) M(20) M(21) M(22) \
               M(23) M(24) M(25) M(26) M(27) M(28) M(29) M(30) M(31)

__device__ __forceinline__ void lstm_scan_dev(ScanSmem* sm, int dir,
                                              const float* __restrict__ xg,
                                              const float* __restrict__ whh,
                                              float* __restrict__ out,
                                              float* __restrict__ gvec, int write_out)
{
    const int tid = threadIdx.x;           // 0..1023
    const int j = tid & (G4 - 1);          // gate row
    const int half = tid >> 9;             // k-half

    const float* wptr = whh + j * HID + half * 64;

    // 32 f16-pair weights pinned in AGPRs (R9: binding proven; no scratch).
#define DECL_PK(p) float apk##p; { \
    f16x2 pk_ = { (_Float16)wptr[2*(p)], (_Float16)wptr[2*(p)+1] }; \
    float bits_ = __builtin_bit_cast(float, pk_); \
    asm volatile("v_accvgpr_write_b32 %0, %1" : "=a"(apk##p) : "v"(bits_)); }
    P32(DECL_PK)
#undef DECL_PK

    if (tid < HID) sm->h16[0][tid] = (_Float16)0.0f;
    float c = 0.0f;
    float msum = 0.0f;
    __syncthreads();

    int t0 = dir ? (T_SEQ - 1) : 0;
    float xv = (half == 0) ? xg[t0 * G4 + j] : 0.0f;

    int pp = 0;
    for (int s = 0; s < T_SEQ; ++s) {
        int s2 = (s + 1 < T_SEQ) ? (s + 1) : s;
        int t      = dir ? (T_SEQ - 1 - s)  : s;
        int t_next = dir ? (T_SEQ - 1 - s2) : s2;
        float xv_n = (half == 0) ? xg[t_next * G4 + j] : 0.0f;

        const f16x8* h16v = reinterpret_cast<const f16x8*>(&sm->h16[pp][half * 64]);
        float acc0 = 0.f, acc1 = 0.f, acc2 = 0.f, acc3 = 0.f;
#define DOT_BLK(i, q0, q1, q2, q3) { f16x8 hv = h16v[i]; float b0_, b1_, b2_, b3_; \
        asm volatile("v_accvgpr_read_b32 %0, %1" : "=v"(b0_) : "a"(apk##q0)); \
        asm volatile("v_accvgpr_read_b32 %0, %1" : "=v"(b1_) : "a"(apk##q1)); \
        asm volatile("v_accvgpr_read_b32 %0, %1" : "=v"(b2_) : "a"(apk##q2)); \
        asm volatile("v_accvgpr_read_b32 %0, %1" : "=v"(b3_) : "a"(apk##q3)); \
        f16x2 h0_ = { hv[0], hv[1] }, h1_ = { hv[2], hv[3] }; \
        f16x2 h2_ = { hv[4], hv[5] }, h3_ = { hv[6], hv[7] }; \
        acc0 = dot2_f16(b0_, h0_, acc0); acc1 = dot2_f16(b1_, h1_, acc1); \
        acc2 = dot2_f16(b2_, h2_, acc2); acc3 = dot2_f16(b3_, h3_, acc3); }
        B8(DOT_BLK)
#undef DOT_BLK
        float p = (acc0 + acc1) + (acc2 + acc3);
        if (half) sm->part[j] = p;
        else      sm->g[j] = p + xv;
        __syncthreads();
        if (tid < HID) {
            float ig = fast_sigmoid(sm->g[tid]           + sm->part[tid]);
            float fg = fast_sigmoid(sm->g[HID + tid]     + sm->part[HID + tid]);
            float gg = fast_tanh(   sm->g[2 * HID + tid] + sm->part[2 * HID + tid]);
            float og = fast_sigmoid(sm->g[3 * HID + tid] + sm->part[3 * HID + tid]);
            c = fg * c + ig * gg;
            float hh = og * fast_tanh(c);
            sm->h16[pp ^ 1][tid] = (_Float16)hh;
            if (write_out) out[t * HID + tid] = hh;
            msum += hh;
        }
        __syncthreads();
        pp ^= 1;
        xv = xv_n;
    }
    if (gvec != nullptr && tid < HID) gvec[dir * HID + tid] = msum * (1.0f / (float)T_SEQ);
}

// ---------------- Combined1: blocks 0-1 = LSTM layer0 scan, rest = CSR gather ----------------
// Volatile 76KB pad keeps 1 block/CU (R14-confirmed scan isolation).
#define GATHER_BLOCKS (N_NODES / 16)          // 3125, 16 waves/block = 1 node/wave
__global__ __launch_bounds__(1024, 1)
void combined1(const float* __restrict__ xg_f, const float* __restrict__ xg_r,
               const float* __restrict__ whh_f, const float* __restrict__ whh_r,
               float* __restrict__ out_f, float* __restrict__ out_r,
               const int* __restrict__ offs, const int* __restrict__ csr_src,
               const float* __restrict__ csr_w, const float* __restrict__ feat,
               float* __restrict__ agg)
{
    __shared__ ScanSmem ssm;
    __shared__ float pad_iso[19456];          // 76 KB occupancy limiter
    volatile float* vpad = pad_iso;           // volatile store: never DCE'd
    vpad[threadIdx.x] = 0.0f;
    int bid = blockIdx.x;
    int tid = threadIdx.x;
    if (bid < 2) {
        lstm_scan_dev(&ssm, bid, bid ? xg_r : xg_f, bid ? whh_r : whh_f,
                      bid ? out_r : out_f, nullptr, 1);
        return;
    }
    // gather path: wave (tid>>6) of this block owns one node
    int n = (bid - 2) * 16 + (tid >> 6);
    int lane = tid & 63;
    int start = offs[n], end = offs[n + 1];
    float ax = 0.0f, ay = 0.0f;
    const float2* f2 = reinterpret_cast<const float2*>(feat);
    for (int e = start; e < end; ++e) {
        int src = csr_src[e];                 // wave-uniform (broadcast)
        float wgt = csr_w[e];
        float2 v = f2[(long)src * 64 + lane]; // coalesced 512B row across wave
        ax += wgt * v.x; ay += wgt * v.y;
    }
    float2 o; o.x = ax; o.y = ay;
    reinterpret_cast<float2*>(agg)[(long)n * 64 + lane] = o;
}

// ---------------- Combined2: blocks <512 = xg1, rest = gconv1 (W1 in LDS) ----------------
#define XG1_BLOCKS 512                        // 2*512*512 threads / 1024
#define NPB2 96
#define G1_BLOCKS ((N_NODES + NPB2 - 1) / NPB2)  // 521
__global__ __launch_bounds__(1024, 1)
void combined2(const float* __restrict__ hf0, const float* __restrict__ hr0,
               const float* __restrict__ wf, const float* __restrict__ bfi, const float* __restrict__ bfh,
               const float* __restrict__ wr, const float* __restrict__ bri, const float* __restrict__ brh,
               float* __restrict__ xg_f, float* __restrict__ xg_r,
               const float* __restrict__ W1, const float* __restrict__ b1,
               float* __restrict__ agg)
{
    __shared__ float w_s[128 * 128];          // 64 KB (gconv1 path)
    __shared__ float row_s[8][HID];
    int bid = blockIdx.x;
    int tid = threadIdx.x;
    if (bid < XG1_BLOCKS) {
        // ---- xg1 path ----
        int gid = bid * 1024 + tid;
        int j = gid & (G4 - 1);
        int rest = gid >> 9;
        int tb = rest & 511;
        int dir = rest >> 9;
        const float* w  = dir ? wr  : wf;
        const float* bi = dir ? bri : bfi;
        const float* bh = dir ? brh : bfh;
        float* xg = dir ? xg_r : xg_f;
        int t0 = tb * 4;

        float b = bi[j] + bh[j];
        float a0 = b, a1 = b, a2 = b, a3 = b;
        const float4* wrow = reinterpret_cast<const float4*>(w + j * 256);
        const float4* hf = reinterpret_cast<const float4*>(hf0 + t0 * HID);
        const float4* hr = reinterpret_cast<const float4*>(hr0 + t0 * HID);
        #pragma unroll 8
        for (int k = 0; k < 32; ++k) {
            float4 wv = wrow[k];
            float4 v0 = hf[k], v1 = hf[32 + k], v2 = hf[64 + k], v3 = hf[96 + k];
            a0 += wv.x*v0.x + wv.y*v0.y + wv.z*v0.z + wv.w*v0.w;
            a1 += wv.x*v1.x + wv.y*v1.y + wv.z*v1.z + wv.w*v1.w;
            a2 += wv.x*v2.x + wv.y*v2.y + wv.z*v2.z + wv.w*v2.w;
            a3 += wv.x*v3.x + wv.y*v3.y + wv.z*v3.z + wv.w*v3.w;
        }
        #pragma unroll 8
        for (int k = 0; k < 32; ++k) {
            float4 wv = wrow[32 + k];
            float4 v0 = hr[k], v1 = hr[32 + k], v2 = hr[64 + k], v3 = hr[96 + k];
            a0 += wv.x*v0.x + wv.y*v0.y + wv.z*v0.z + wv.w*v0.w;
            a1 += wv.x*v1.x + wv.y*v1.y + wv.z*v1.z + wv.w*v1.w;
            a2 += wv.x*v2.x + wv.y*v2.y + wv.z*v2.z + wv.w*v2.w;
            a3 += wv.x*v3.x + wv.y*v3.y + wv.z*v3.z + wv.w*v3.w;
        }
        xg[(t0 + 0) * G4 + j] = a0;
        xg[(t0 + 1) * G4 + j] = a1;
        xg[(t0 + 2) * G4 + j] = a2;
        xg[(t0 + 3) * G4 + j] = a3;
        return;
    }
    // ---- gconv1 path: linear+relu in-place on agg ----
    int gb = bid - XG1_BLOCKS;
    int j = tid & 127;
    int sub = tid >> 7;                        // 0..7 rows in flight
    for (int i = tid; i < 128 * 128; i += 1024) w_s[i] = W1[i];
    float bj = b1[j];
    __syncthreads();
    int base = gb * NPB2;
    for (int n0 = base; n0 < base + NPB2; n0 += 8) {
        int row = n0 + sub;
        bool valid = row < N_NODES;
        if (valid) row_s[sub][j] = agg[(long)row * HID + j];
        __syncthreads();
        float a = bj;
        #pragma unroll 8
        for (int k = 0; k < 128; ++k) a += row_s[sub][k] * w_s[k * 128 + j];
        __syncthreads();
        if (valid) agg[(long)row * HID + j] = fmaxf(a, 0.0f);
    }
}

// ---------------- Combined3: blocks 0-1 = LSTM layer1 scan, rest = outw reduce ----------------
// R16 observation: combined3's scan (no pad, 4 blocks/CU co-residency) ran
// slower than combined1's isolated scan. Apply the same volatile-pad
// isolation here: 72 KB pad + 8.7 KB -> 82.4 KB > 80 KB -> 1 block/CU.
#define RED_BLOCKS 512
__global__ __launch_bounds__(1024, 1)
void combined3(const float* __restrict__ xg_f, const float* __restrict__ xg_r,
               const float* __restrict__ whh_f, const float* __restrict__ whh_r,
               float* __restrict__ gvec,
               const float* __restrict__ outw, const float* __restrict__ h,
               float* __restrict__ s_out)
{
    __shared__ ScanSmem ssm;
    __shared__ float red[8 * 128];
    __shared__ float pad_iso[18432];          // 72 KB occupancy limiter
    volatile float* vpad = pad_iso;           // volatile store: never DCE'd
    vpad[threadIdx.x] = 0.0f;
    int bid = blockIdx.x;
    int tid = threadIdx.x;
    if (bid < 2) {
        lstm_scan_dev(&ssm, bid, bid ? xg_r : xg_f, bid ? whh_r : whh_f,
                      nullptr, gvec, 0);
        return;
    }
    int hb = bid - 2;                          // 0..RED_BLOCKS-1
    int f = tid & 127;
    int r = tid >> 7;                          // 0..7
    float acc = 0.0f;
    for (int n = hb * 8 + r; n < N_NODES; n += RED_BLOCKS * 8)
        acc += outw[n] * h[(long)n * HID + f];
    red[r * 128 + f] = acc;
    __syncthreads();
    if (tid < 128) {
        float s = 0.0f;
        #pragma unroll
        for (int rr = 0; rr < 8; ++rr) s += red[rr * 128 + tid];
        atomicAdd(&s_out[tid], s);
    }
}

// ---------------- head: hg = (s/N)@W2 + b2; concat; 4-layer MLP ----------------
__global__ __launch_bounds__(640)
void head_kernel(const float* __restrict__ s_in, const float* __restrict__ W2, const float* __restrict__ b2,
                 const float* __restrict__ gvec, const float* __restrict__ kmer,
                 const float* __restrict__ fc1w, const float* __restrict__ fc1b,
                 const float* __restrict__ fc2w, const float* __restrict__ fc2b,
                 const float* __restrict__ fc3w, const float* __restrict__ fc3b,
                 const float* __restrict__ fc4w, const float* __restrict__ fc4b,
                 float* __restrict__ out)
{
    __shared__ float feat[1152];
    __shared__ float a1[576];
    __shared__ float a2[256];
    __shared__ float a3[64];
    int tid = threadIdx.x;
    if (tid < 256) {
        float acc = b2[tid];
        const float inv_n = 1.0f / (float)N_NODES;
        for (int k = 0; k < HID; ++k)
            acc += (s_in[k] * inv_n) * W2[k * 256 + tid];
        feat[tid] = acc;
    } else if (tid < 512) {
        feat[tid] = gvec[tid - 256];
    }
    if (tid < 638) feat[512 + tid] = kmer[tid];
    __syncthreads();

    if (tid < 575) {
        const float2* wr = reinterpret_cast<const float2*>(fc1w + (long)tid * 1150);
        const float2* f2 = reinterpret_cast<const float2*>(feat);
        float acc = fc1b[tid];
        for (int k = 0; k < 575; ++k) {
            float2 wv = wr[k]; float2 fv = f2[k];
            acc += wv.x * fv.x + wv.y * fv.y;
        }
        a1[tid] = fmaxf(acc, 0.0f);
    }
    __syncthreads();
    if (tid < 256) {
        const float* wr = fc2w + (long)tid * 575;
        float acc = fc2b[tid];
        for (int k = 0; k < 575; ++k) acc += a1[k] * wr[k];
        a2[tid] = fmaxf(acc, 0.0f);
    }
    __syncthreads();
    if (tid < 64) {
        const float4* wr = reinterpret_cast<const float4*>(fc3w + (long)tid * 256);
        const float4* av4 = reinterpret_cast<const float4*>(a2);
        float acc = fc3b[tid];
        for (int k = 0; k < 64; ++k) {
            float4 wv = wr[k]; float4 av = av4[k];
            acc += wv.x*av.x + wv.y*av.y + wv.z*av.z + wv.w*av.w;
        }
        a3[tid] = fmaxf(acc, 0.0f);
    }
    __syncthreads();
    if (tid == 0) {
        float acc = fc4b[0];
        for (int k = 0; k < 64; ++k) acc += a3[k] * fc4w[k];
        out[0] = acc;
    }
}

extern "C" void kernel_launch(void* const* d_in, const int* in_sizes, int n_in,
                              void* d_out, int out_size, void* d_ws, size_t ws_size,
                              hipStream_t stream)
{
    const float* g_mol = (const float*)d_in[0];
    const float* feat  = (const float*)d_in[1];
    const int*   esrc  = (const int*)d_in[2];
    const int*   edst  = (const int*)d_in[3];
    const float* ew    = (const float*)d_in[4];
    const float* kmer  = (const float*)d_in[5];
    const float* w_ih_l0  = (const float*)d_in[6];
    const float* w_hh_l0  = (const float*)d_in[7];
    const float* b_ih_l0  = (const float*)d_in[8];
    const float* b_hh_l0  = (const float*)d_in[9];
    const float* w_ih_l0r = (const float*)d_in[10];
    const float* w_hh_l0r = (const float*)d_in[11];
    const float* b_ih_l0r = (const float*)d_in[12];
    const float* b_hh_l0r = (const float*)d_in[13];
    const float* w_ih_l1  = (const float*)d_in[14];
    const float* w_hh_l1  = (const float*)d_in[15];
    const float* b_ih_l1  = (const float*)d_in[16];
    const float* b_hh_l1  = (const float*)d_in[17];
    const float* w_ih_l1r = (const float*)d_in[18];
    const float* w_hh_l1r = (const float*)d_in[19];
    const float* b_ih_l1r = (const float*)d_in[20];
    const float* b_hh_l1r = (const float*)d_in[21];
    const float* W1 = (const float*)d_in[22];
    const float* b1 = (const float*)d_in[23];
    const float* W2 = (const float*)d_in[24];
    const float* b2 = (const float*)d_in[25];
    const float* fc1w = (const float*)d_in[26];
    const float* fc1b = (const float*)d_in[27];
    const float* fc2w = (const float*)d_in[28];
    const float* fc2b = (const float*)d_in[29];
    const float* fc3w = (const float*)d_in[30];
    const float* fc3b = (const float*)d_in[31];
    const float* fc4w = (const float*)d_in[32];
    const float* fc4b = (const float*)d_in[33];

    float* ws  = (float*)d_ws;
    float* XGF  = ws;                          // [2048*512]
    float* XGR  = XGF + T_SEQ * G4;            // [2048*512]
    float* HF0  = XGR + T_SEQ * G4;            // [2048*128]
    float* HR0  = HF0 + T_SEQ * HID;           // [2048*128]
    float* GVEC = HR0 + T_SEQ * HID;           // [256]
    float* SUM  = GVEC + 256;                  // [128]
    float* AGG  = SUM + 128;                   // [50000*128]
    float* OUTW = AGG + (size_t)N_NODES * HID; // [50000]
    float* CSRW = OUTW + N_NODES;              // [800000]
    int*   CNT  = (int*)(CSRW + N_EDGES);      // [50001]
    int*   OFFS = CNT + (N_NODES + 4);         // [50001]
    int*   CURS = OFFS + (N_NODES + 4);        // [50001]
    int*   CSRS = CURS + (N_NODES + 4);        // [800000]

    hipMemsetAsync(SUM, 0, 128 * sizeof(float), stream);
    hipMemsetAsync(OUTW, 0, N_NODES * sizeof(float), stream);
    hipMemsetAsync(CNT, 0, (N_NODES + 4) * sizeof(int), stream);

    // 0. CSR build (by dst) + out-weight (by src)
    hist_kernel<<<EDGE_BLOCKS, 1024, 0, stream>>>(esrc, edst, ew, CNT, OUTW);
    prefix_kernel<<<1, 1024, 0, stream>>>(CNT, OFFS, CURS);
    reorder_kernel<<<EDGE_BLOCKS, 1024, 0, stream>>>(esrc, edst, ew, CURS, CSRS, CSRW);

    // 1. xg0 (layer-0 input gates)
    xg0_kernel<<<(2 * T_SEQ * G4) / 256, 256, 0, stream>>>(
        g_mol, w_ih_l0, b_ih_l0, b_hh_l0, w_ih_l0r, b_ih_l0r, b_hh_l0r, XGF, XGR);

    // 2. scan layer0 (2 blocks, CU-exclusive) || CSR gather hop1 (no atomics)
    combined1<<<2 + GATHER_BLOCKS, 1024, 0, stream>>>(
        XGF, XGR, w_hh_l0, w_hh_l0r, HF0, HR0, OFFS, CSRS, CSRW, feat, AGG);

    // 3. xg1 (512 blocks, needs scan0) || gconv1 (521 blocks, needs gather)
    combined2<<<XG1_BLOCKS + G1_BLOCKS, 1024, 0, stream>>>(
        HF0, HR0, w_ih_l1, b_ih_l1, b_hh_l1, w_ih_l1r, b_ih_l1r, b_hh_l1r,
        XGF, XGR, W1, b1, AGG);

    // 4. scan layer1 (2 blocks, CU-exclusive) || outw-weighted node reduce
    combined3<<<2 + RED_BLOCKS, 1024, 0, stream>>>(
        XGF, XGR, w_hh_l1, w_hh_l1r, GVEC, OUTW, AGG, SUM);

    // 5. head
    head_kernel<<<1, 640, 0, stream>>>(SUM, W2, b2, GVEC, kmer,
                                       fc1w, fc1b, fc2w, fc2b, fc3w, fc3b, fc4w, fc4b,
                                       (float*)d_out);
}

// Round 18
// 4466.369 us; speedup vs baseline: 1.2036x; 1.0239x over previous
//
#include <hip/hip_runtime.h>
#include <hip/hip_bf16.h>

#define T_SEQ 2048
#define HID 128
#define G4 512           // 4*HID gates
#define N_NODES 50000
#define N_EDGES 800000

typedef float f32x4 __attribute__((ext_vector_type(4)));
typedef _Float16 f16x2 __attribute__((ext_vector_type(2)));
typedef _Float16 f16x8 __attribute__((ext_vector_type(8)));

__device__ __forceinline__ float fast_sigmoid(float x) {
    return 1.0f / (1.0f + __expf(-x));
}
__device__ __forceinline__ float fast_tanh(float x) {
    return 1.0f - 2.0f / (__expf(2.0f * x) + 1.0f);
}

__device__ __forceinline__ float dot2_f16(float bits_w, f16x2 h2, float acc) {
    f16x2 w2 = __builtin_bit_cast(f16x2, bits_w);
#if __has_builtin(__builtin_amdgcn_fdot2)
    return __builtin_amdgcn_fdot2(w2, h2, acc, false);
#else
    asm("v_dot2_f32_f16 %0, %1, %2, %0" : "+v"(acc) : "v"(w2), "v"(h2));
    return acc;
#endif
}

// ---------------- fused0: blocks <HIST_BLOCKS = edge histogram, rest = xg0 ----------------
#define HIST_BLOCKS ((N_EDGES + 1023) / 1024)      // 782
#define XG0_BLOCKS ((2 * T_SEQ * G4) / 1024)       // 2048
__global__ void fused0_kernel(const int* __restrict__ esrc, const int* __restrict__ edst,
                              const float* __restrict__ ew,
                              int* __restrict__ cnt, float* __restrict__ outw,
                              const float* __restrict__ g_mol,
                              const float* __restrict__ wf, const float* __restrict__ bfi, const float* __restrict__ bfh,
                              const float* __restrict__ wr, const float* __restrict__ bri, const float* __restrict__ brh,
                              float* __restrict__ xg_f, float* __restrict__ xg_r)
{
    int bid = blockIdx.x;
    int tid = threadIdx.x;
    if (bid < HIST_BLOCKS) {
        int e = bid * 1024 + tid;
        if (e < N_EDGES) {
            atomicAdd(&cnt[edst[e]], 1);
            atomicAdd(&outw[esrc[e]], ew[e]);
        }
        return;
    }
    int gid = (bid - HIST_BLOCKS) * 1024 + tid;
    int j = gid & (G4 - 1);
    int rest = gid >> 9;
    int t = rest & (T_SEQ - 1);
    int dir = rest >> 11;
    const float* w  = dir ? wr  : wf;
    const float* bi = dir ? bri : bfi;
    const float* bh = dir ? brh : bfh;
    float* xg = dir ? xg_r : xg_f;
    const float* x  = g_mol + t * 17;
    const float* wj = w + j * 17;
    float acc = bi[j] + bh[j];
    #pragma unroll
    for (int k = 0; k < 17; ++k) acc += x[k] * wj[k];
    xg[t * G4 + j] = acc;
}

// single-block exclusive prefix over cnt -> offs, cursor
__global__ __launch_bounds__(1024)
void prefix_kernel(const int* __restrict__ cnt, int* __restrict__ offs, int* __restrict__ cursor)
{
    __shared__ int part[1024];
    const int tid = threadIdx.x;
    const int CH = (N_NODES + 1023) / 1024;   // 49
    int base = tid * CH;
    int sum = 0;
    for (int i = 0; i < CH; ++i) { int idx = base + i; if (idx < N_NODES) sum += cnt[idx]; }
    part[tid] = sum;
    __syncthreads();
    for (int d = 1; d < 1024; d <<= 1) {
        int v = (tid >= d) ? part[tid - d] : 0;
        __syncthreads();
        part[tid] += v;
        __syncthreads();
    }
    int run = (tid == 0) ? 0 : part[tid - 1];
    for (int i = 0; i < CH; ++i) {
        int idx = base + i;
        if (idx < N_NODES) { offs[idx] = run; cursor[idx] = run; run += cnt[idx]; }
    }
    if (tid == 1023) offs[N_NODES] = run;
}

__global__ void reorder_kernel(const int* __restrict__ esrc, const int* __restrict__ edst,
                               const float* __restrict__ ew, int* __restrict__ cursor,
                               int* __restrict__ csr_src, float* __restrict__ csr_w)
{
    int e = blockIdx.x * 1024 + threadIdx.x;
    if (e < N_EDGES) {
        int pos = atomicAdd(&cursor[edst[e]], 1);
        csr_src[pos] = esrc[e];
        csr_w[pos]   = ew[e];
    }
}

// ---------------- xg1 standalone (no LDS -> full occupancy) ----------------
#define XG1_BLOCKS 512                        // 2*512*512 threads / 1024
__global__ void xg1_kernel(const float* __restrict__ hf0, const float* __restrict__ hr0,
                           const float* __restrict__ wf, const float* __restrict__ bfi, const float* __restrict__ bfh,
                           const float* __restrict__ wr, const float* __restrict__ bri, const float* __restrict__ brh,
                           float* __restrict__ xg_f, float* __restrict__ xg_r)
{
    int gid = blockIdx.x * 1024 + threadIdx.x;
    int j = gid & (G4 - 1);
    int rest = gid >> 9;
    int tb = rest & 511;
    int dir = rest >> 9;
    const float* w  = dir ? wr  : wf;
    const float* bi = dir ? bri : bfi;
    const float* bh = dir ? brh : bfh;
    float* xg = dir ? xg_r : xg_f;
    int t0 = tb * 4;

    float b = bi[j] + bh[j];
    float a0 = b, a1 = b, a2 = b, a3 = b;
    const float4* wrow = reinterpret_cast<const float4*>(w + j * 256);
    const float4* hf = reinterpret_cast<const float4*>(hf0 + t0 * HID);
    const float4* hr = reinterpret_cast<const float4*>(hr0 + t0 * HID);
    #pragma unroll 8
    for (int k = 0; k < 32; ++k) {
        float4 wv = wrow[k];
        float4 v0 = hf[k], v1 = hf[32 + k], v2 = hf[64 + k], v3 = hf[96 + k];
        a0 += wv.x*v0.x + wv.y*v0.y + wv.z*v0.z + wv.w*v0.w;
        a1 += wv.x*v1.x + wv.y*v1.y + wv.z*v1.z + wv.w*v1.w;
        a2 += wv.x*v2.x + wv.y*v2.y + wv.z*v2.z + wv.w*v2.w;
        a3 += wv.x*v3.x + wv.y*v3.y + wv.z*v3.z + wv.w*v3.w;
    }
    #pragma unroll 8
    for (int k = 0; k < 32; ++k) {
        float4 wv = wrow[32 + k];
        float4 v0 = hr[k], v1 = hr[32 + k], v2 = hr[64 + k], v3 = hr[96 + k];
        a0 += wv.x*v0.x + wv.y*v0.y + wv.z*v0.z + wv.w*v0.w;
        a1 += wv.x*v1.x + wv.y*v1.y + wv.z*v1.z + wv.w*v1.w;
        a2 += wv.x*v2.x + wv.y*v2.y + wv.z*v2.z + wv.w*v2.w;
        a3 += wv.x*v3.x + wv.y*v3.y + wv.z*v3.z + wv.w*v3.w;
    }
    xg[(t0 + 0) * G4 + j] = a0;
    xg[(t0 + 1) * G4 + j] = a1;
    xg[(t0 + 2) * G4 + j] = a2;
    xg[(t0 + 3) * G4 + j] = a3;
}

// ---------------- shared-memory layout + device scan (R11/R15 dot2+AGPR engine) ----------------
// Proven best (R16: no activation replication, no shuffles in serial path).
struct ScanSmem {
    _Float16 h16[2][HID] __attribute__((aligned(16)));
    float g[G4];
    float part[G4];
};

#define B8(M) M(0,0,1,2,3) M(1,4,5,6,7) M(2,8,9,10,11) M(3,12,13,14,15) \
              M(4,16,17,18,19) M(5,20,21,22,23) M(6,24,25,26,27) M(7,28,29,30,31)
#define P32(M) M(0) M(1) M(2) M(3) M(4) M(5) M(6) M(7) M(8) M(9) M(10) M(11) \
               M(12) M(13) M(14) M(15) M(16) M(17) M(18) M(19) M(20) M(21) M(22) \
               M(23) M(24) M(25) M(26) M(27) M(28) M(29) M(30) M(31)

__device__ __forceinline__ void lstm_scan_dev(ScanSmem* sm, int dir,
                                              const float* __restrict__ xg,
                                              const float* __restrict__ whh,
                                              float* __restrict__ out,
                                              float* __restrict__ gvec, int write_out)
{
    const int tid = threadIdx.x;           // 0..1023
    const int j = tid & (G4 - 1);          // gate row
    const int half = tid >> 9;             // k-half

    const float* wptr = whh + j * HID + half * 64;

#define DECL_PK(p) float apk##p; { \
    f16x2 pk_ = { (_Float16)wptr[2*(p)], (_Float16)wptr[2*(p)+1] }; \
    float bits_ = __builtin_bit_cast(float, pk_); \
    asm volatile("v_accvgpr_write_b32 %0, %1" : "=a"(apk##p) : "v"(bits_)); }
    P32(DECL_PK)
#undef DECL_PK

    if (tid < HID) sm->h16[0][tid] = (_Float16)0.0f;
    float c = 0.0f;
    float msum = 0.0f;
    __syncthreads();

    int t0 = dir ? (T_SEQ - 1) : 0;
    float xv = (half == 0) ? xg[t0 * G4 + j] : 0.0f;

    int pp = 0;
    for (int s = 0; s < T_SEQ; ++s) {
        int s2 = (s + 1 < T_SEQ) ? (s + 1) : s;
        int t      = dir ? (T_SEQ - 1 - s)  : s;
        int t_next = dir ? (T_SEQ - 1 - s2) : s2;
        float xv_n = (half == 0) ? xg[t_next * G4 + j] : 0.0f;

        const f16x8* h16v = reinterpret_cast<const f16x8*>(&sm->h16[pp][half * 64]);
        float acc0 = 0.f, acc1 = 0.f, acc2 = 0.f, acc3 = 0.f;
#define DOT_BLK(i, q0, q1, q2, q3) { f16x8 hv = h16v[i]; float b0_, b1_, b2_, b3_; \
        asm volatile("v_accvgpr_read_b32 %0, %1" : "=v"(b0_) : "a"(apk##q0)); \
        asm volatile("v_accvgpr_read_b32 %0, %1" : "=v"(b1_) : "a"(apk##q1)); \
        asm volatile("v_accvgpr_read_b32 %0, %1" : "=v"(b2_) : "a"(apk##q2)); \
        asm volatile("v_accvgpr_read_b32 %0, %1" : "=v"(b3_) : "a"(apk##q3)); \
        f16x2 h0_ = { hv[0], hv[1] }, h1_ = { hv[2], hv[3] }; \
        f16x2 h2_ = { hv[4], hv[5] }, h3_ = { hv[6], hv[7] }; \
        acc0 = dot2_f16(b0_, h0_, acc0); acc1 = dot2_f16(b1_, h1_, acc1); \
        acc2 = dot2_f16(b2_, h2_, acc2); acc3 = dot2_f16(b3_, h3_, acc3); }
        B8(DOT_BLK)
#undef DOT_BLK
        float p = (acc0 + acc1) + (acc2 + acc3);
        if (half) sm->part[j] = p;
        else      sm->g[j] = p + xv;
        __syncthreads();
        if (tid < HID) {
            float ig = fast_sigmoid(sm->g[tid]           + sm->part[tid]);
            float fg = fast_sigmoid(sm->g[HID + tid]     + sm->part[HID + tid]);
            float gg = fast_tanh(   sm->g[2 * HID + tid] + sm->part[2 * HID + tid]);
            float og = fast_sigmoid(sm->g[3 * HID + tid] + sm->part[3 * HID + tid]);
            c = fg * c + ig * gg;
            float hh = og * fast_tanh(c);
            sm->h16[pp ^ 1][tid] = (_Float16)hh;
            if (write_out) out[t * HID + tid] = hh;
            msum += hh;
        }
        __syncthreads();
        pp ^= 1;
        xv = xv_n;
    }
    if (gvec != nullptr && tid < HID) gvec[dir * HID + tid] = msum * (1.0f / (float)T_SEQ);
}

// ---------------- Combined1: blocks 0-1 = LSTM layer0 scan, rest = CSR gather ----------------
#define GATHER_BLOCKS (N_NODES / 16)          // 3125, 16 waves/block = 1 node/wave
__global__ __launch_bounds__(1024, 1)
void combined1(const float* __restrict__ xg_f, const float* __restrict__ xg_r,
               const float* __restrict__ whh_f, const float* __restrict__ whh_r,
               float* __restrict__ out_f, float* __restrict__ out_r,
               const int* __restrict__ offs, const int* __restrict__ csr_src,
               const float* __restrict__ csr_w, const float* __restrict__ feat,
               float* __restrict__ agg)
{
    __shared__ ScanSmem ssm;
    __shared__ float pad_iso[19456];          // 76 KB -> 82432 B total -> 1 block/CU
    volatile float* vpad = pad_iso;
    vpad[threadIdx.x] = 0.0f;
    int bid = blockIdx.x;
    int tid = threadIdx.x;
    if (bid < 2) {
        lstm_scan_dev(&ssm, bid, bid ? xg_r : xg_f, bid ? whh_r : whh_f,
                      bid ? out_r : out_f, nullptr, 1);
        return;
    }
    // gather path: wave (tid>>6) of this block owns one node
    int n = (bid - 2) * 16 + (tid >> 6);
    int lane = tid & 63;
    int start = offs[n], end = offs[n + 1];
    float ax = 0.0f, ay = 0.0f;
    const float2* f2 = reinterpret_cast<const float2*>(feat);
    for (int e = start; e < end; ++e) {
        int src = csr_src[e];
        float wgt = csr_w[e];
        float2 v = f2[(long)src * 64 + lane];
        ax += wgt * v.x; ay += wgt * v.y;
    }
    float2 o; o.x = ax; o.y = ay;
    reinterpret_cast<float2*>(agg)[(long)n * 64 + lane] = o;
}

// ---------------- Combined3: blocks 0-1 = scan1, rest = gconv1 + FUSED reduce ----------------
// SUM[f] = sum_n outw[n] * relu(agg[n]@W1 + b1)[f] — h never written to global.
#define NPB2 96
#define G1_BLOCKS ((N_NODES + NPB2 - 1) / NPB2)  // 521
__global__ __launch_bounds__(1024, 1)
void combined3(const float* __restrict__ xg_f, const float* __restrict__ xg_r,
               const float* __restrict__ whh_f, const float* __restrict__ whh_r,
               float* __restrict__ gvec,
               const float* __restrict__ W1, const float* __restrict__ b1,
               const float* __restrict__ agg, const float* __restrict__ outw,
               float* __restrict__ s_out)
{
    __shared__ ScanSmem ssm;                   // 4608 B
    __shared__ float w_s[128 * 128];           // 64 KB
    __shared__ float row_s[8][HID];            // 4 KB
    __shared__ float red[8][HID];              // 4 KB
    __shared__ float pad_iso[2048];            // 8 KB -> total 84.8 KB -> 1 block/CU
    volatile float* vpad = pad_iso;
    vpad[threadIdx.x & 2047] = 0.0f;
    int bid = blockIdx.x;
    int tid = threadIdx.x;
    if (bid < 2) {
        lstm_scan_dev(&ssm, bid, bid ? xg_r : xg_f, bid ? whh_r : whh_f,
                      nullptr, gvec, 0);
        return;
    }
    // gconv1 + reduce path
    int gb = bid - 2;
    int j = tid & 127;
    int sub = tid >> 7;                        // 0..7 rows in flight
    for (int i = tid; i < 128 * 128; i += 1024) w_s[i] = W1[i];
    float bj = b1[j];
    float sacc = 0.0f;
    __syncthreads();
    int base = gb * NPB2;
    for (int n0 = base; n0 < base + NPB2; n0 += 8) {
        int row = n0 + sub;
        bool valid = row < N_NODES;
        if (valid) row_s[sub][j] = agg[(long)row * HID + j];
        __syncthreads();
        float a = bj;
        #pragma unroll 8
        for (int k = 0; k < 128; ++k) a += row_s[sub][k] * w_s[k * 128 + j];
        __syncthreads();
        if (valid) sacc += outw[row] * fmaxf(a, 0.0f);
    }
    red[sub][j] = sacc;
    __syncthreads();
    if (tid < 128) {
        float s = 0.0f;
        #pragma unroll
        for (int rr = 0; rr < 8; ++rr) s += red[rr][tid];
        atomicAdd(&s_out[tid], s);
    }
}

// ---------------- head: hg = (s/N)@W2 + b2; concat; 4-layer MLP ----------------
__global__ __launch_bounds__(640)
void head_kernel(const float* __restrict__ s_in, const float* __restrict__ W2, const float* __restrict__ b2,
                 const float* __restrict__ gvec, const float* __restrict__ kmer,
                 const float* __restrict__ fc1w, const float* __restrict__ fc1b,
                 const float* __restrict__ fc2w, const float* __restrict__ fc2b,
                 const float* __restrict__ fc3w, const float* __restrict__ fc3b,
                 const float* __restrict__ fc4w, const float* __restrict__ fc4b,
                 float* __restrict__ out)
{
    __shared__ float feat[1152];
    __shared__ float a1[576];
    __shared__ float a2[256];
    __shared__ float a3[64];
    int tid = threadIdx.x;
    if (tid < 256) {
        float acc = b2[tid];
        const float inv_n = 1.0f / (float)N_NODES;
        for (int k = 0; k < HID; ++k)
            acc += (s_in[k] * inv_n) * W2[k * 256 + tid];
        feat[tid] = acc;
    } else if (tid < 512) {
        feat[tid] = gvec[tid - 256];
    }
    if (tid < 638) feat[512 + tid] = kmer[tid];
    __syncthreads();

    if (tid < 575) {
        const float2* wr = reinterpret_cast<const float2*>(fc1w + (long)tid * 1150);
        const float2* f2 = reinterpret_cast<const float2*>(feat);
        float acc = fc1b[tid];
        for (int k = 0; k < 575; ++k) {
            float2 wv = wr[k]; float2 fv = f2[k];
            acc += wv.x * fv.x + wv.y * fv.y;
        }
        a1[tid] = fmaxf(acc, 0.0f);
    }
    __syncthreads();
    if (tid < 256) {
        const float* wr = fc2w + (long)tid * 575;
        float acc = fc2b[tid];
        for (int k = 0; k < 575; ++k) acc += a1[k] * wr[k];
        a2[tid] = fmaxf(acc, 0.0f);
    }
    __syncthreads();
    if (tid < 64) {
        const float4* wr = reinterpret_cast<const float4*>(fc3w + (long)tid * 256);
        const float4* av4 = reinterpret_cast<const float4*>(a2);
        float acc = fc3b[tid];
        for (int k = 0; k < 64; ++k) {
            float4 wv = wr[k]; float4 av = av4[k];
            acc += wv.x*av.x + wv.y*av.y + wv.z*av.z + wv.w*av.w;
        }
        a3[tid] = fmaxf(acc, 0.0f);
    }
    __syncthreads();
    if (tid == 0) {
        float acc = fc4b[0];
        for (int k = 0; k < 64; ++k) acc += a3[k] * fc4w[k];
        out[0] = acc;
    }
}

extern "C" void kernel_launch(void* const* d_in, const int* in_sizes, int n_in,
                              void* d_out, int out_size, void* d_ws, size_t ws_size,
                              hipStream_t stream)
{
    const float* g_mol = (const float*)d_in[0];
    const float* feat  = (const float*)d_in[1];
    const int*   esrc  = (const int*)d_in[2];
    const int*   edst  = (const int*)d_in[3];
    const float* ew    = (const float*)d_in[4];
    const float* kmer  = (const float*)d_in[5];
    const float* w_ih_l0  = (const float*)d_in[6];
    const float* w_hh_l0  = (const float*)d_in[7];
    const float* b_ih_l0  = (const float*)d_in[8];
    const float* b_hh_l0  = (const float*)d_in[9];
    const float* w_ih_l0r = (const float*)d_in[10];
    const float* w_hh_l0r = (const float*)d_in[11];
    const float* b_ih_l0r = (const float*)d_in[12];
    const float* b_hh_l0r = (const float*)d_in[13];
    const float* w_ih_l1  = (const float*)d_in[14];
    const float* w_hh_l1  = (const float*)d_in[15];
    const float* b_ih_l1  = (const float*)d_in[16];
    const float* b_hh_l1  = (const float*)d_in[17];
    const float* w_ih_l1r = (const float*)d_in[18];
    const float* w_hh_l1r = (const float*)d_in[19];
    const float* b_ih_l1r = (const float*)d_in[20];
    const float* b_hh_l1r = (const float*)d_in[21];
    const float* W1 = (const float*)d_in[22];
    const float* b1 = (const float*)d_in[23];
    const float* W2 = (const float*)d_in[24];
    const float* b2 = (const float*)d_in[25];
    const float* fc1w = (const float*)d_in[26];
    const float* fc1b = (const float*)d_in[27];
    const float* fc2w = (const float*)d_in[28];
    const float* fc2b = (const float*)d_in[29];
    const float* fc3w = (const float*)d_in[30];
    const float* fc3b = (const float*)d_in[31];
    const float* fc4w = (const float*)d_in[32];
    const float* fc4b = (const float*)d_in[33];

    float* ws  = (float*)d_ws;
    float* XGF  = ws;                          // [2048*512]
    float* XGR  = XGF + T_SEQ * G4;            // [2048*512]
    float* HF0  = XGR + T_SEQ * G4;            // [2048*128]
    float* HR0  = HF0 + T_SEQ * HID;           // [2048*128]
    float* GVEC = HR0 + T_SEQ * HID;           // [256]
    float* SUM  = GVEC + 256;                  // [128]
    float* AGG  = SUM + 128;                   // [50000*128]
    float* OUTW = AGG + (size_t)N_NODES * HID; // [50000]
    float* CSRW = OUTW + N_NODES;              // [800000]
    int*   CNT  = (int*)(CSRW + N_EDGES);      // [50001]
    int*   OFFS = CNT + (N_NODES + 4);         // [50001]
    int*   CURS = OFFS + (N_NODES + 4);        // [50001]
    int*   CSRS = CURS + (N_NODES + 4);        // [800000]

    hipMemsetAsync(SUM, 0, 128 * sizeof(float), stream);
    hipMemsetAsync(OUTW, 0, N_NODES * sizeof(float), stream);
    hipMemsetAsync(CNT, 0, (N_NODES + 4) * sizeof(int), stream);

    // 0. hist (by dst/src) || xg0 — independent, fused
    fused0_kernel<<<HIST_BLOCKS + XG0_BLOCKS, 1024, 0, stream>>>(
        esrc, edst, ew, CNT, OUTW,
        g_mol, w_ih_l0, b_ih_l0, b_hh_l0, w_ih_l0r, b_ih_l0r, b_hh_l0r, XGF, XGR);
    prefix_kernel<<<1, 1024, 0, stream>>>(CNT, OFFS, CURS);
    reorder_kernel<<<HIST_BLOCKS, 1024, 0, stream>>>(esrc, edst, ew, CURS, CSRS, CSRW);

    // 1. scan layer0 (2 blocks, CU-exclusive) || CSR gather hop1 (no atomics)
    combined1<<<2 + GATHER_BLOCKS, 1024, 0, stream>>>(
        XGF, XGR, w_hh_l0, w_hh_l0r, HF0, HR0, OFFS, CSRS, CSRW, feat, AGG);

    // 2. xg1 standalone (no LDS, full occupancy)
    xg1_kernel<<<XG1_BLOCKS, 1024, 0, stream>>>(
        HF0, HR0, w_ih_l1, b_ih_l1, b_hh_l1, w_ih_l1r, b_ih_l1r, b_hh_l1r, XGF, XGR);

    // 3. scan layer1 (2 blocks, CU-exclusive) || gconv1+fused hop2 reduce
    combined3<<<2 + G1_BLOCKS, 1024, 0, stream>>>(
        XGF, XGR, w_hh_l1, w_hh_l1r, GVEC, W1, b1, AGG, OUTW, SUM);

    // 4. head
    head_kernel<<<1, 640, 0, stream>>>(SUM, W2, b2, GVEC, kmer,
                                       fc1w, fc1b, fc2w, fc2b, fc3w, fc3b, fc4w, fc4b,
                                       (float*)d_out);
}